// Round 11
// baseline (619.610 us; speedup 1.0000x reference)
//
#include <hip/hip_runtime.h>
#include <hip/hip_bf16.h>
#include <math.h>

#define NN 50000
#define NE 1000000
#define NIMAG 200000
#define NBLOCK 5000
#define HID 128
#define NB_SCAN ((NN + 255) / 256)   // 196

typedef __attribute__((ext_vector_type(8))) short bf16x8;
typedef __attribute__((ext_vector_type(4))) float f32x4;

__device__ inline unsigned short f2bf(float x) {
    unsigned u = __float_as_uint(x);
    unsigned r = u + 0x7fff + ((u >> 16) & 1);   // RNE
    return (unsigned short)(r >> 16);
}
__device__ inline float bf2f(unsigned short b) {
    return __uint_as_float((unsigned)b << 16);
}
// load 4 bf16 (8B) -> float4
__device__ inline float4 ld_bf4(const short* p) {
    uint2 d = *(const uint2*)p;
    float4 o;
    o.x = __uint_as_float(d.x << 16);
    o.y = __uint_as_float(d.x & 0xffff0000u);
    o.z = __uint_as_float(d.y << 16);
    o.w = __uint_as_float(d.y & 0xffff0000u);
    return o;
}

// ---------------- zero fill ----------------
__global__ void zero_k(int* __restrict__ p, int n) {
    int i = blockIdx.x * 256 + threadIdx.x;
    if (i < n) p[i] = 0;
}

// ---------------- CSR build ----------------
__global__ void count_k(const int* __restrict__ ei, int* __restrict__ counts) {
    int e = blockIdx.x * 256 + threadIdx.x;
    if (e < NE) atomicAdd(&counts[ei[NE + e]], 1);
}

__global__ void scan1_k(const int* __restrict__ counts, int* __restrict__ offs,
                        int* __restrict__ bsum) {
    __shared__ int sh[256];
    int t = threadIdx.x;
    int i = blockIdx.x * 256 + t;
    int v = (i < NN) ? counts[i] : 0;
    sh[t] = v;
    __syncthreads();
    for (int off = 1; off < 256; off <<= 1) {
        int a = (t >= off) ? sh[t - off] : 0;
        __syncthreads();
        sh[t] += a;
        __syncthreads();
    }
    if (i < NN) offs[i] = sh[t] - v;
    if (t == 255) bsum[blockIdx.x] = sh[255];
}

__global__ void scan2_k(const int* __restrict__ bsum, int* __restrict__ bscan,
                        int* __restrict__ offs) {
    __shared__ int sh[256];
    int t = threadIdx.x;
    int v = (t < NB_SCAN) ? bsum[t] : 0;
    sh[t] = v;
    __syncthreads();
    for (int off = 1; off < 256; off <<= 1) {
        int a = (t >= off) ? sh[t - off] : 0;
        __syncthreads();
        sh[t] += a;
        __syncthreads();
    }
    if (t < NB_SCAN) bscan[t] = sh[t] - v;
    if (t == NB_SCAN - 1) offs[NN] = sh[t];
}

__global__ void scan3_k(int* __restrict__ offs, const int* __restrict__ bscan) {
    int i = blockIdx.x * 256 + threadIdx.x;
    if (i < NN) offs[i] += bscan[blockIdx.x];
}

__global__ void scatter_k(const int* __restrict__ ei, const int* __restrict__ offs,
                          int* __restrict__ counts, int* __restrict__ csr_src) {
    int e = blockIdx.x * 256 + threadIdx.x;
    if (e < NE) {
        int d = ei[NE + e];
        int pos = offs[d] + atomicSub(&counts[d], 1) - 1;
        csr_src[pos] = ei[e];
    }
}

// ---------------- batched W pre-convert: fp32 [K][N] -> split-bf16 [N][K] ----
struct WDesc { const float* src; short* dh; short* dl; int K; int N; };
struct WDescs { WDesc d[14]; };
__global__ __launch_bounds__(256) void wconv_k(WDescs ds) {
    int m = blockIdx.x >> 7;
    int i = (blockIdx.x & 127) * 256 + threadIdx.x;
    WDesc w = ds.d[m];
    int tot = w.K * w.N;
    if (i < tot) {
        int k = i / w.N, n = i - k * w.N;
        float v = w.src[i];
        unsigned short h = f2bf(v);
        w.dh[(size_t)n * w.K + k] = (short)h;
        w.dl[(size_t)n * w.K + k] = (short)f2bf(v - bf2f(h));
    }
}

__global__ void biascat_k(const float* __restrict__ bl, const float* __restrict__ br,
                          float* __restrict__ o) {
    int l = blockIdx.x, t = threadIdx.x;
    o[l * 256 + t] = (t < 128) ? bl[l * 128 + t] : br[l * 128 + (t - 128)];
}

// ---------------- LDS layout: [64][128] shorts, XOR-swizzled 16B chunks ----
template <int NTW>
__device__ inline void stage_mfma(
    const short* __restrict__ Wh, const short* __restrict__ Wl,
    int Kstride, int kb,
    const short (*Ash)[128], const short (*Asl)[128],
    int w, int llo, int lhi, f32x4 (&acc)[4][NTW])
{
#pragma unroll
    for (int ks = 0; ks < 4; ++ks) {
        bf16x8 wf_h[NTW], wf_l[NTW];
#pragma unroll
        for (int nt = 0; nt < NTW; ++nt) {
            int n = (w * NTW + nt) * 16 + llo;
            size_t off = (size_t)n * Kstride + kb + ks * 32 + lhi * 8;
            wf_h[nt] = *(const bf16x8*)(Wh + off);
            wf_l[nt] = *(const bf16x8*)(Wl + off);
        }
        bf16x8 ba_h[4], ba_l[4];
#pragma unroll
        for (int mt = 0; mt < 4; ++mt) {
            int m = mt * 16 + llo;
            int c = ((4 * ks + lhi) ^ llo) << 3;
            ba_h[mt] = *(const bf16x8*)&Ash[m][c];
            ba_l[mt] = *(const bf16x8*)&Asl[m][c];
        }
#pragma unroll
        for (int mt = 0; mt < 4; ++mt)
#pragma unroll
            for (int nt = 0; nt < NTW; ++nt) {
                acc[mt][nt] = __builtin_amdgcn_mfma_f32_16x16x32_bf16(
                    wf_h[nt], ba_h[mt], acc[mt][nt], 0, 0, 0);
                acc[mt][nt] = __builtin_amdgcn_mfma_f32_16x16x32_bf16(
                    wf_h[nt], ba_l[mt], acc[mt][nt], 0, 0, 0);
                acc[mt][nt] = __builtin_amdgcn_mfma_f32_16x16x32_bf16(
                    wf_l[nt], ba_h[mt], acc[mt][nt], 0, 0, 0);
            }
    }
}

// A plain bf16 (hi plane only): 2 MFMAs per product (a.wh + a.wl)
template <int NTW>
__device__ inline void stage_mfma_h(
    const short* __restrict__ Wh, const short* __restrict__ Wl,
    int Kstride, int kb,
    const short (*Ash)[128],
    int w, int llo, int lhi, f32x4 (&acc)[4][NTW])
{
#pragma unroll
    for (int ks = 0; ks < 4; ++ks) {
        bf16x8 wf_h[NTW], wf_l[NTW];
#pragma unroll
        for (int nt = 0; nt < NTW; ++nt) {
            int n = (w * NTW + nt) * 16 + llo;
            size_t off = (size_t)n * Kstride + kb + ks * 32 + lhi * 8;
            wf_h[nt] = *(const bf16x8*)(Wh + off);
            wf_l[nt] = *(const bf16x8*)(Wl + off);
        }
        bf16x8 ba[4];
#pragma unroll
        for (int mt = 0; mt < 4; ++mt) {
            int m = mt * 16 + llo;
            int c = ((4 * ks + lhi) ^ llo) << 3;
            ba[mt] = *(const bf16x8*)&Ash[m][c];
        }
#pragma unroll
        for (int mt = 0; mt < 4; ++mt)
#pragma unroll
            for (int nt = 0; nt < NTW; ++nt) {
                acc[mt][nt] = __builtin_amdgcn_mfma_f32_16x16x32_bf16(
                    wf_h[nt], ba[mt], acc[mt][nt], 0, 0, 0);
                acc[mt][nt] = __builtin_amdgcn_mfma_f32_16x16x32_bf16(
                    wf_l[nt], ba[mt], acc[mt][nt], 0, 0, 0);
            }
    }
}

// act = relu(acc + bias) -> split-bf16 back into LDS A planes (swizzled)
__device__ inline void act_to_lds(
    f32x4 (&acc)[4][2], const float* __restrict__ bias,
    short (*Ash)[128], short (*Asl)[128], int w, int llo, int lhi)
{
#pragma unroll
    for (int mt = 0; mt < 4; ++mt) {
        int r = mt * 16 + llo;
#pragma unroll
        for (int nt = 0; nt < 2; ++nt) {
            int c0 = (w * 2 + nt) * 16 + lhi * 4;
            int chunk = c0 >> 3;
            int off = ((chunk ^ llo) << 3) + (c0 & 7);
            short4 h4, l4;
            short* hp = (short*)&h4; short* lp = (short*)&l4;
#pragma unroll
            for (int u = 0; u < 4; ++u) {
                float z = acc[mt][nt][u] + bias[c0 + u];
                z = z > 0.f ? z : 0.f;
                unsigned short hb = f2bf(z);
                hp[u] = (short)hb;
                lp[u] = (short)f2bf(z - bf2f(hb));
            }
            *(short4*)&Ash[r][off] = h4;
            *(short4*)&Asl[r][off] = l4;
        }
    }
}

// per-thread register chunks for gather staging
struct AChunk { bf16x8 h[4], l[4]; };
struct AChunkH { bf16x8 h[4]; };

template <bool DUAL>
__device__ inline void gather_chunk(
    AChunk& c,
    const short* __restrict__ A0h, const short* __restrict__ A0l, int ld0, int K0,
    const short* __restrict__ A1h, const short* __restrict__ A1l, int ld1,
    const int* __restrict__ idx0, const int* __restrict__ idx1,
    int kb, int row0, int M, int t)
{
#pragma unroll
    for (int j = 0; j < 4; ++j) {
        int u = j * 256 + t;
        int lr = u >> 4, q = u & 15;
        int gr = row0 + lr; if (gr >= M) gr = M - 1;
        int kk = kb + q * 8;
        const short *bh, *bl; int ld, lk; const int* idx;
        if (!DUAL || kk < K0) { bh = A0h; bl = A0l; ld = ld0; lk = kk; idx = idx0; }
        else                  { bh = A1h; bl = A1l; ld = ld1; lk = kk - K0; idx = idx1; }
        int sr = idx ? idx[gr] : gr;
        size_t off = (size_t)sr * ld + lk;
        c.h[j] = *(const bf16x8*)(bh + off);
        c.l[j] = *(const bf16x8*)(bl + off);
    }
}

template <bool DUAL>
__device__ inline void gather_chunk_h(
    AChunkH& c,
    const short* __restrict__ A0, int ld0, int K0,
    const short* __restrict__ A1, int ld1,
    const int* __restrict__ idx0, const int* __restrict__ idx1,
    int kb, int row0, int M, int t)
{
#pragma unroll
    for (int j = 0; j < 4; ++j) {
        int u = j * 256 + t;
        int lr = u >> 4, q = u & 15;
        int gr = row0 + lr; if (gr >= M) gr = M - 1;
        int kk = kb + q * 8;
        const short* b; int ld, lk; const int* idx;
        if (!DUAL || kk < K0) { b = A0; ld = ld0; lk = kk; idx = idx0; }
        else                  { b = A1; ld = ld1; lk = kk - K0; idx = idx1; }
        int sr = idx ? idx[gr] : gr;
        c.h[j] = *(const bf16x8*)(b + (size_t)sr * ld + lk);
    }
}

__device__ inline void write_chunk(const AChunk& c,
                                   short (*Ash)[128], short (*Asl)[128], int t)
{
#pragma unroll
    for (int j = 0; j < 4; ++j) {
        int u = j * 256 + t;
        int lr = u >> 4, q = u & 15;
        int off = ((q ^ (lr & 15)) << 3);
        *(bf16x8*)&Ash[lr][off] = c.h[j];
        *(bf16x8*)&Asl[lr][off] = c.l[j];
    }
}

__device__ inline void write_chunk_h(const AChunkH& c, short (*Ash)[128], int t)
{
#pragma unroll
    for (int j = 0; j < 4; ++j) {
        int u = j * 256 + t;
        int lr = u >> 4, q = u & 15;
        int off = ((q ^ (lr & 15)) << 3);
        *(bf16x8*)&Ash[lr][off] = c.h[j];
    }
}

// ---------------- fused MLP chain (2 or 3 MFMA stages in one dispatch) -----
// h activations live interleaved: row stride 256 shorts, hi at +0, lo at +128.
// FINAL: 0 = write interleaved split rows (stride 256), 1 = FDOT sigmoid, 2 = fp32 NOUT.
// AHALF: stage-1 A gathered hi-plane-only (plain bf16, 2-MFMA products) — edec.
template <int K1, int NSTAGE, int NOUT, int FINAL, bool INS, bool AHALF>
__global__ __launch_bounds__(256, 2) void mlp_k(
    const void* __restrict__ A0h, const void* __restrict__ A0l, int ld0, int K0,
    const void* __restrict__ A1h, const void* __restrict__ A1l, int ld1,
    const int* __restrict__ idx0, const int* __restrict__ idx1,
    const short* __restrict__ W1h, const short* __restrict__ W1l, const float* __restrict__ b1,
    const short* __restrict__ W2h, const short* __restrict__ W2l, const float* __restrict__ b2,
    const short* __restrict__ W3h, const short* __restrict__ W3l, const float* __restrict__ b3,
    short* __restrict__ Ch, short* __restrict__ Cl, float* __restrict__ Cf,
    const float* __restrict__ Wd, const float* __restrict__ bd, float* __restrict__ outd,
    int M)
{
    __shared__ __align__(16) short As_h[64][128];
    __shared__ __align__(16) short As_l[64][128];
    __shared__ float redf[4][64];

    const int t = threadIdx.x;
    const int w = t >> 6, lane = t & 63;
    const int llo = lane & 15, lhi = lane >> 4;
    const int row0 = blockIdx.x * 64;

    // ---- stage 1 ----
    f32x4 acc1[4][2];
#pragma unroll
    for (int mt = 0; mt < 4; ++mt)
#pragma unroll
        for (int nt = 0; nt < 2; ++nt) { f32x4 z = {0,0,0,0}; acc1[mt][nt] = z; }

    if (AHALF) {
        // K1 == 256, hi-plane gathers; both row-gathers issued up-front.
        AChunkH c0, c1;
        gather_chunk_h<true>(c0, (const short*)A0h, ld0, K0,
                             (const short*)A1h, ld1, idx0, idx1, 0, row0, M, t);
        gather_chunk_h<true>(c1, (const short*)A0h, ld0, K0,
                             (const short*)A1h, ld1, idx0, idx1, 128, row0, M, t);
        write_chunk_h(c0, As_h, t);
        __syncthreads();
        stage_mfma_h<2>(W1h, W1l, K1, 0, As_h, w, llo, lhi, acc1);
        __syncthreads();   // WAR guard
        write_chunk_h(c1, As_h, t);
        __syncthreads();
        stage_mfma_h<2>(W1h, W1l, K1, 128, As_h, w, llo, lhi, acc1);
    } else if (INS) {
        AChunk c;
        gather_chunk<(K1 == 256)>(c, (const short*)A0h, (const short*)A0l, ld0, K0,
                                  (const short*)A1h, (const short*)A1l, ld1,
                                  idx0, idx1, 0, row0, M, t);
        write_chunk(c, As_h, As_l, t);
        __syncthreads();
        stage_mfma<2>(W1h, W1l, K1, 0, As_h, As_l, w, llo, lhi, acc1);
        if (K1 == 256) {
            __syncthreads();
            gather_chunk<true>(c, (const short*)A0h, (const short*)A0l, ld0, K0,
                               (const short*)A1h, (const short*)A1l, ld1,
                               idx0, idx1, 128, row0, M, t);
            write_chunk(c, As_h, As_l, t);
            __syncthreads();
            stage_mfma<2>(W1h, W1l, K1, 128, As_h, As_l, w, llo, lhi, acc1);
        }
    } else {
        // fp32 A (encoder layer 0): convert during staging, K1=128
#pragma unroll
        for (int j = 0; j < 8; ++j) {
            int u = j * 256 + t;
            int lr = u >> 5;
            int q  = u & 31;
            int gr = row0 + lr; if (gr >= M) gr = M - 1;
            int kk = q * 4;
            const float* src; int ld, lk; const int* idx;
            if (kk < K0) { src = (const float*)A0h; ld = ld0; lk = kk; idx = idx0; }
            else         { src = (const float*)A1h; ld = ld1; lk = kk - K0; idx = idx1; }
            int sr = idx ? idx[gr] : gr;
            float4 v = *(const float4*)(src + (size_t)sr * ld + lk);
            float xs[4] = {v.x, v.y, v.z, v.w};
            short4 h4, l4;
            short* hp = (short*)&h4; short* lp = (short*)&l4;
#pragma unroll
            for (int i = 0; i < 4; ++i) {
                unsigned short hb = f2bf(xs[i]);
                hp[i] = (short)hb;
                lp[i] = (short)f2bf(xs[i] - bf2f(hb));
            }
            int off = (((q >> 1) ^ (lr & 15)) << 3) + (q & 1) * 4;
            *(short4*)&As_h[lr][off] = h4;
            *(short4*)&As_l[lr][off] = l4;
        }
        __syncthreads();
        stage_mfma<2>(W1h, W1l, K1, 0, As_h, As_l, w, llo, lhi, acc1);
    }
    __syncthreads();                 // all stage-1 LDS reads done
    act_to_lds(acc1, b1, As_h, As_l, w, llo, lhi);
    __syncthreads();

    // ---- stage 2 ----
    f32x4 acc2[4][2];
#pragma unroll
    for (int mt = 0; mt < 4; ++mt)
#pragma unroll
        for (int nt = 0; nt < 2; ++nt) { f32x4 z = {0,0,0,0}; acc2[mt][nt] = z; }
    stage_mfma<2>(W2h, W2l, 128, 0, As_h, As_l, w, llo, lhi, acc2);

    if (NSTAGE == 2) {
        // FDOT epilogue: out[r] = sigmoid(relu(acc2+b2) . Wd + bd)
        const float bdd = bd[0];
        float pd[4] = {0.f, 0.f, 0.f, 0.f};
#pragma unroll
        for (int mt = 0; mt < 4; ++mt)
#pragma unroll
            for (int nt = 0; nt < 2; ++nt) {
                int c0 = (w * 2 + nt) * 16 + lhi * 4;
#pragma unroll
                for (int u = 0; u < 4; ++u) {
                    float z = acc2[mt][nt][u] + b2[c0 + u];
                    z = z > 0.f ? z : 0.f;
                    pd[mt] = fmaf(z, Wd[c0 + u], pd[mt]);
                }
            }
#pragma unroll
        for (int mt = 0; mt < 4; ++mt) {
            pd[mt] += __shfl_xor(pd[mt], 16, 64);
            pd[mt] += __shfl_xor(pd[mt], 32, 64);
        }
        if (lhi == 0) {
#pragma unroll
            for (int mt = 0; mt < 4; ++mt) redf[w][mt * 16 + llo] = pd[mt];
        }
        __syncthreads();
        if (w == 0 && lhi == 0) {
#pragma unroll
            for (int mt = 0; mt < 4; ++mt) {
                int r = row0 + mt * 16 + llo;
                if (r < M) {
                    float d = redf[0][mt * 16 + llo] + redf[1][mt * 16 + llo]
                            + redf[2][mt * 16 + llo] + redf[3][mt * 16 + llo] + bdd;
                    outd[r] = 1.f / (1.f + __expf(-d));
                }
            }
        }
    } else {
        __syncthreads();
        act_to_lds(acc2, b2, As_h, As_l, w, llo, lhi);
        __syncthreads();
        // ---- stage 3 ----
        constexpr int NTWF = NOUT / 64;
        f32x4 acc3[4][NTWF];
#pragma unroll
        for (int mt = 0; mt < 4; ++mt)
#pragma unroll
            for (int nt = 0; nt < NTWF; ++nt) { f32x4 z = {0,0,0,0}; acc3[mt][nt] = z; }
        stage_mfma<NTWF>(W3h, W3l, 128, 0, As_h, As_l, w, llo, lhi, acc3);
#pragma unroll
        for (int mt = 0; mt < 4; ++mt) {
            int r = row0 + mt * 16 + llo;
            if (r < M) {
#pragma unroll
                for (int nt = 0; nt < NTWF; ++nt) {
                    int c0 = (w * NTWF + nt) * 16 + lhi * 4;
                    float v[4];
#pragma unroll
                    for (int u = 0; u < 4; ++u) v[u] = acc3[mt][nt][u] + b3[c0 + u];
                    if (FINAL == 0) {
                        short4 h4, l4;
                        short* hp = (short*)&h4; short* lp = (short*)&l4;
#pragma unroll
                        for (int u = 0; u < 4; ++u) {
                            unsigned short hb = f2bf(v[u]);
                            hp[u] = (short)hb;
                            lp[u] = (short)f2bf(v[u] - bf2f(hb));
                        }
                        *(short4*)(Ch + (size_t)r * 256 + c0) = h4;   // interleaved rows
                        *(short4*)(Cl + (size_t)r * 256 + c0) = l4;   // Cl = Ch + 128
                    } else {
                        float4 o = {v[0], v[1], v[2], v[3]};
                        *(float4*)(Cf + (size_t)r * NOUT + c0) = o;
                    }
                }
            }
        }
    }
}

// ---------------- N=256 GEMM for fused xl||xr -> bf16 rows [NN][256] -------
__global__ __launch_bounds__(256, 2) void gemmlr_k(
    const short* __restrict__ h,     // interleaved split rows, stride 256
    const short* __restrict__ Wh, const short* __restrict__ Wl,
    const float* __restrict__ bias, short* __restrict__ C, int M)
{
    __shared__ __align__(16) short As_h[64][128];
    __shared__ __align__(16) short As_l[64][128];
    const int t = threadIdx.x;
    const int w = t >> 6, lane = t & 63;
    const int llo = lane & 15, lhi = lane >> 4;
    const int row0 = blockIdx.x * 64;

    f32x4 acc[4][4];
#pragma unroll
    for (int mt = 0; mt < 4; ++mt)
#pragma unroll
        for (int nt = 0; nt < 4; ++nt) { f32x4 z = {0,0,0,0}; acc[mt][nt] = z; }

#pragma unroll
    for (int j = 0; j < 4; ++j) {
        int u = j * 256 + t;
        int lr = u >> 4;
        int q  = u & 15;
        int gr = row0 + lr; if (gr >= M) gr = M - 1;
        size_t off = (size_t)gr * 256 + q * 8;
        int loff = ((q ^ (lr & 15)) << 3);
        *(bf16x8*)&As_h[lr][loff] = *(const bf16x8*)(h + off);
        *(bf16x8*)&As_l[lr][loff] = *(const bf16x8*)(h + off + 128);
    }
    __syncthreads();
    stage_mfma<4>(Wh, Wl, 128, 0, As_h, As_l, w, llo, lhi, acc);

#pragma unroll
    for (int mt = 0; mt < 4; ++mt) {
        int r = row0 + mt * 16 + llo;
        if (r < M) {
#pragma unroll
            for (int nt = 0; nt < 4; ++nt) {
                int c0 = (w * 4 + nt) * 16 + lhi * 4;
                short4 o;
                short* op = (short*)&o;
#pragma unroll
                for (int u = 0; u < 4; ++u)
                    op[u] = (short)f2bf(acc[mt][nt][u] + bias[c0 + u]);
                *(short4*)(C + (size_t)r * 256 + c0) = o;
            }
        }
    }
}

// ---------------- GATv2: half-wave per edge, bf16 rows, DPP logit reduce ---
#define GPH 6
#define NEGI -1e30f
#define DPPADD(v, ctrl) \
    v += __int_as_float(__builtin_amdgcn_update_dpp(0, __float_as_int(v), ctrl, 0xf, 0xf, true))

__device__ inline float red32_bcast(float v) {
    DPPADD(v, 0x111);   // row_shr:1
    DPPADD(v, 0x112);   // row_shr:2
    DPPADD(v, 0x114);   // row_shr:4
    DPPADD(v, 0x118);   // row_shr:8
    DPPADD(v, 0x142);   // row_bcast15 -> lane31 holds 32-sum
    return __int_as_float(__builtin_amdgcn_ds_swizzle(__float_as_int(v), 0x03E0));
}

__global__ __launch_bounds__(256) void gat2_k(
    const short* __restrict__ xlr,   // bf16 rows [NN][256]: xl | xr
    const float* __restrict__ att,
    const int* __restrict__ offs, const int* __restrict__ csrs,
    const float* __restrict__ bias,
    short* __restrict__ hout)        // interleaved split rows, stride 256
{
    const int wid = (blockIdx.x * 256 + threadIdx.x) >> 6;
    const int lane = threadIdx.x & 63;
    const int h = lane >> 5, sub = lane & 31;
    if (wid >= NN) return;
    const int n = wid;
    const int beg = offs[n];
    const int total = (offs[n + 1] - beg) + 1;

    const float4 attv = *(const float4*)(att + sub * 4);
    const float4 xrv  = ld_bf4(xlr + (size_t)n * 256 + 128 + sub * 4);

    float m = NEGI, s = 0.f;
    float4 acc = {0.f, 0.f, 0.f, 0.f};

    int cs[GPH];
#pragma unroll
    for (int p = 0; p < GPH; ++p) {
        int slot = p * 2 + h;
        cs[p] = (slot < total) ? ((slot == 0) ? n : csrs[beg + slot - 1]) : n;
    }

    for (int base = 0; base < total; base += 2 * GPH) {
        float4 r[GPH];
#pragma unroll
        for (int p = 0; p < GPH; ++p)
            r[p] = ld_bf4(xlr + (size_t)cs[p] * 256 + sub * 4);
        int ns[GPH];
#pragma unroll
        for (int p = 0; p < GPH; ++p) {
            int nslot = base + 2 * GPH + p * 2 + h;
            ns[p] = (nslot < total) ? csrs[beg + nslot - 1] : n;
        }
        float e[GPH];
#pragma unroll
        for (int p = 0; p < GPH; ++p) {
            float v = 0.f;
#pragma unroll
            for (int j = 0; j < 4; ++j) {
                float mj = ((const float*)&r[p])[j] + ((const float*)&xrv)[j];
                mj = mj > 0.f ? mj : 0.2f * mj;
                v = fmaf(mj, ((const float*)&attv)[j], v);
            }
            v = red32_bcast(v);
            e[p] = (base + p * 2 + h < total) ? v : NEGI;
        }
        float tm = fmaxf(fmaxf(fmaxf(e[0], e[1]), fmaxf(e[2], e[3])),
                         fmaxf(e[4], e[5]));
        float mnew = fmaxf(m, tm);
        float sc = __expf(m - mnew);
        s *= sc; acc.x *= sc; acc.y *= sc; acc.z *= sc; acc.w *= sc;
#pragma unroll
        for (int p = 0; p < GPH; ++p) {
            float wj = __expf(e[p] - mnew);
            s += wj;
            acc.x = fmaf(wj, r[p].x, acc.x);
            acc.y = fmaf(wj, r[p].y, acc.y);
            acc.z = fmaf(wj, r[p].z, acc.z);
            acc.w = fmaf(wj, r[p].w, acc.w);
        }
        m = mnew;
#pragma unroll
        for (int p = 0; p < GPH; ++p) cs[p] = ns[p];
    }
    // merge halves
    float om = __shfl_xor(m, 32, 64);
    float os = __shfl_xor(s, 32, 64);
    float4 oacc;
    oacc.x = __shfl_xor(acc.x, 32, 64);
    oacc.y = __shfl_xor(acc.y, 32, 64);
    oacc.z = __shfl_xor(acc.z, 32, 64);
    oacc.w = __shfl_xor(acc.w, 32, 64);
    float M = fmaxf(m, om);
    float a = __expf(m - M), b = __expf(om - M);
    float st = s * a + os * b;
    float inv = 1.f / st;
    if (h == 0) {
        float ov[4];
        ov[0] = (acc.x * a + oacc.x * b) * inv + bias[sub * 4 + 0];
        ov[1] = (acc.y * a + oacc.y * b) * inv + bias[sub * 4 + 1];
        ov[2] = (acc.z * a + oacc.z * b) * inv + bias[sub * 4 + 2];
        ov[3] = (acc.w * a + oacc.w * b) * inv + bias[sub * 4 + 3];
        short4 h4, l4;
        short* hp = (short*)&h4; short* lp = (short*)&l4;
#pragma unroll
        for (int u = 0; u < 4; ++u) {
            unsigned short hb = f2bf(ov[u]);
            hp[u] = (short)hb;
            lp[u] = (short)f2bf(ov[u] - bf2f(hb));
        }
        *(short4*)(hout + (size_t)n * 256 + sub * 4) = h4;
        *(short4*)(hout + (size_t)n * 256 + 128 + sub * 4) = l4;
    }
}

extern "C" void kernel_launch(void* const* d_in, const int* in_sizes, int n_in,
                              void* d_out, int out_size, void* d_ws, size_t ws_size,
                              hipStream_t stream)
{
    const float* x    = (const float*)d_in[0];
    const float* emb  = (const float*)d_in[1];
    const int*   ei   = (const int*)d_in[2];
    const int*   bidx = (const int*)d_in[3];
    const int*   eim  = (const int*)d_in[4];
    const float* encW = (const float*)d_in[5];
    const float* encB = (const float*)d_in[6];
    const float* gWl  = (const float*)d_in[7];
    const float* gbl  = (const float*)d_in[8];
    const float* gWr  = (const float*)d_in[9];
    const float* gbr  = (const float*)d_in[10];
    const float* gatt = (const float*)d_in[11];
    const float* gb   = (const float*)d_in[12];
    const float* eW0  = (const float*)d_in[13];
    const float* eb0  = (const float*)d_in[14];
    const float* eW1  = (const float*)d_in[15];
    const float* eb1  = (const float*)d_in[16];
    const float* eW2  = (const float*)d_in[17];
    const float* eb2  = (const float*)d_in[18];
    const float* nW0  = (const float*)d_in[19];
    const float* nb0  = (const float*)d_in[20];
    const float* nW1  = (const float*)d_in[21];
    const float* nb1  = (const float*)d_in[22];
    const float* nW2  = (const float*)d_in[23];
    const float* nb2  = (const float*)d_in[24];
    float* out = (float*)d_out;

    char* wptr = (char*)d_ws;
    auto alloc = [&](size_t bytes) {
        char* p = wptr;
        wptr += (bytes + 255) & ~(size_t)255;
        return p;
    };
    short* h    = (short*)alloc((size_t)NN * 256 * 2);   // interleaved hi|lo rows
    short* xlrb = (short*)alloc((size_t)NN * 256 * 2);   // bf16 xl|xr rows
    int* counts = (int*)alloc((size_t)NN * 4);
    int* offs   = (int*)alloc((size_t)(NN + 1) * 4);
    int* csrs   = (int*)alloc((size_t)NE * 4);
    int* bsum   = (int*)alloc(256 * 4);
    int* bscan  = (int*)alloc(256 * 4);
    auto wplane = [&](int elems, short*& ph, short*& pl) {
        ph = (short*)alloc((size_t)elems * 2);
        pl = (short*)alloc((size_t)elems * 2);
    };
    short *encWt_h[3], *encWt_l[3];
    for (int i = 0; i < 3; ++i) wplane(HID * HID, encWt_h[i], encWt_l[i]);
    short *glrt_h[3], *glrt_l[3];
    for (int i = 0; i < 3; ++i) wplane(256 * HID, glrt_h[i], glrt_l[i]);
    short *eW0t_h, *eW0t_l, *eW1t_h, *eW1t_l;
    wplane(2 * HID * HID, eW0t_h, eW0t_l);
    wplane(HID * HID, eW1t_h, eW1t_l);
    short *nW0t_h, *nW0t_l, *nW1t_h, *nW1t_l, *nW2t_h, *nW2t_l;
    wplane(HID * HID, nW0t_h, nW0t_l);
    wplane(HID * HID, nW1t_h, nW1t_l);
    wplane(HID * 64, nW2t_h, nW2t_l);
    float* gblr = (float*)alloc(3 * 256 * 4);

    // ---- W pre-conversion ----
    WDescs ds;
    int di = 0;
    for (int i = 0; i < 3; ++i)
        ds.d[di++] = {encW + (size_t)i * HID * HID, encWt_h[i], encWt_l[i], HID, HID};
    for (int i = 0; i < 3; ++i) {
        ds.d[di++] = {gWl + (size_t)i * HID * HID, glrt_h[i], glrt_l[i], HID, HID};
        ds.d[di++] = {gWr + (size_t)i * HID * HID, glrt_h[i] + HID * HID,
                      glrt_l[i] + HID * HID, HID, HID};
    }
    ds.d[di++] = {eW0, eW0t_h, eW0t_l, 2 * HID, HID};
    ds.d[di++] = {eW1, eW1t_h, eW1t_l, HID, HID};
    ds.d[di++] = {nW0, nW0t_h, nW0t_l, HID, HID};
    ds.d[di++] = {nW1, nW1t_h, nW1t_l, HID, HID};
    ds.d[di++] = {nW2, nW2t_h, nW2t_l, HID, 64};
    wconv_k<<<14 * 128, 256, 0, stream>>>(ds);
    biascat_k<<<3, 256, 0, stream>>>(gbl, gbr, gblr);

    // ---- CSR build ----
    zero_k<<<(NN + 255) / 256, 256, 0, stream>>>(counts, NN);
    count_k<<<(NE + 255) / 256, 256, 0, stream>>>(ei, counts);
    scan1_k<<<NB_SCAN, 256, 0, stream>>>(counts, offs, bsum);
    scan2_k<<<1, 256, 0, stream>>>(bsum, bscan, offs);
    scan3_k<<<NB_SCAN, 256, 0, stream>>>(offs, bscan);
    scatter_k<<<(NE + 255) / 256, 256, 0, stream>>>(ei, offs, counts, csrs);

    const int gN = (NN + 63) / 64;
    // ---- encoder MLP: one fused dispatch (3 stages) -> interleaved h ----
    mlp_k<128, 3, 128, 0, false, false><<<gN, 256, 0, stream>>>(
        x, nullptr, 64, 64, emb, nullptr, 64, nullptr, nullptr,
        encWt_h[0], encWt_l[0], encB,
        encWt_h[1], encWt_l[1], encB + 128,
        encWt_h[2], encWt_l[2], encB + 256,
        h, h + 128, nullptr, nullptr, nullptr, nullptr, NN);

    // ---- 3 GATv2 layers ----
    const int gGAT = (NN * 64 + 255) / 256;
    for (int l = 0; l < 3; ++l) {
        gemmlr_k<<<gN, 256, 0, stream>>>(h, glrt_h[l], glrt_l[l],
                                         gblr + (size_t)l * 256, xlrb, NN);
        gat2_k<<<gGAT, 256, 0, stream>>>(xlrb, gatt + (size_t)l * HID,
                                         offs, csrs, gb + (size_t)l * HID, h);
    }

    // ---- edge decoder: single fused dispatch, hi-plane gathers ----
    mlp_k<256, 2, 128, 1, true, true><<<(NIMAG + 63) / 64, 256, 0, stream>>>(
        h, nullptr, 256, 128, h, nullptr, 256, eim, eim + NIMAG,
        eW0t_h, eW0t_l, eb0,
        eW1t_h, eW1t_l, eb1,
        nullptr, nullptr, nullptr,
        nullptr, nullptr, nullptr,
        eW2, eb2, out + (size_t)NBLOCK * 64, NIMAG);

    // ---- node decoder: one fused dispatch (3 stages) ----
    mlp_k<128, 3, 64, 2, true, false><<<(NBLOCK + 63) / 64, 256, 0, stream>>>(
        h, h + 128, 256, 128, nullptr, nullptr, 0, bidx, nullptr,
        nW0t_h, nW0t_l, nb0,
        nW1t_h, nW1t_l, nb1,
        nW2t_h, nW2t_l, nb2,
        nullptr, nullptr, out, nullptr, nullptr, nullptr, NBLOCK);
}

// Round 12
// 602.584 us; speedup vs baseline: 1.0283x; 1.0283x over previous
//
#include <hip/hip_runtime.h>
#include <hip/hip_bf16.h>
#include <math.h>

#define NN 50000
#define NE 1000000
#define NIMAG 200000
#define NBLOCK 5000
#define HID 128
#define NB_SCAN ((NN + 255) / 256)   // 196

typedef __attribute__((ext_vector_type(8))) short bf16x8;
typedef __attribute__((ext_vector_type(4))) float f32x4;

__device__ inline unsigned short f2bf(float x) {
    unsigned u = __float_as_uint(x);
    unsigned r = u + 0x7fff + ((u >> 16) & 1);   // RNE
    return (unsigned short)(r >> 16);
}
__device__ inline float bf2f(unsigned short b) {
    return __uint_as_float((unsigned)b << 16);
}
// load 4 bf16 (8B) -> float4
__device__ inline float4 ld_bf4(const short* p) {
    uint2 d = *(const uint2*)p;
    float4 o;
    o.x = __uint_as_float(d.x << 16);
    o.y = __uint_as_float(d.x & 0xffff0000u);
    o.z = __uint_as_float(d.y << 16);
    o.w = __uint_as_float(d.y & 0xffff0000u);
    return o;
}

// ---------------- zero fill ----------------
__global__ void zero_k(int* __restrict__ p, int n) {
    int i = blockIdx.x * 256 + threadIdx.x;
    if (i < n) p[i] = 0;
}

// ---------------- CSR build ----------------
__global__ void count_k(const int* __restrict__ ei, int* __restrict__ counts) {
    int e = blockIdx.x * 256 + threadIdx.x;
    if (e < NE) atomicAdd(&counts[ei[NE + e]], 1);
}

__global__ void scan1_k(const int* __restrict__ counts, int* __restrict__ offs,
                        int* __restrict__ bsum) {
    __shared__ int sh[256];
    int t = threadIdx.x;
    int i = blockIdx.x * 256 + t;
    int v = (i < NN) ? counts[i] : 0;
    sh[t] = v;
    __syncthreads();
    for (int off = 1; off < 256; off <<= 1) {
        int a = (t >= off) ? sh[t - off] : 0;
        __syncthreads();
        sh[t] += a;
        __syncthreads();
    }
    if (i < NN) offs[i] = sh[t] - v;
    if (t == 255) bsum[blockIdx.x] = sh[255];
}

__global__ void scan2_k(const int* __restrict__ bsum, int* __restrict__ bscan,
                        int* __restrict__ offs) {
    __shared__ int sh[256];
    int t = threadIdx.x;
    int v = (t < NB_SCAN) ? bsum[t] : 0;
    sh[t] = v;
    __syncthreads();
    for (int off = 1; off < 256; off <<= 1) {
        int a = (t >= off) ? sh[t - off] : 0;
        __syncthreads();
        sh[t] += a;
        __syncthreads();
    }
    if (t < NB_SCAN) bscan[t] = sh[t] - v;
    if (t == NB_SCAN - 1) offs[NN] = sh[t];
}

__global__ void scan3_k(int* __restrict__ offs, const int* __restrict__ bscan) {
    int i = blockIdx.x * 256 + threadIdx.x;
    if (i < NN) offs[i] += bscan[blockIdx.x];
}

__global__ void scatter_k(const int* __restrict__ ei, const int* __restrict__ offs,
                          int* __restrict__ counts, int* __restrict__ csr_src) {
    int e = blockIdx.x * 256 + threadIdx.x;
    if (e < NE) {
        int d = ei[NE + e];
        int pos = offs[d] + atomicSub(&counts[d], 1) - 1;
        csr_src[pos] = ei[e];
    }
}

// ---------------- batched W pre-convert: fp32 [K][N] -> split-bf16 [N][K] ----
struct WDesc { const float* src; short* dh; short* dl; int K; int N; };
struct WDescs { WDesc d[14]; };
__global__ __launch_bounds__(256) void wconv_k(WDescs ds) {
    int m = blockIdx.x >> 7;
    int i = (blockIdx.x & 127) * 256 + threadIdx.x;
    WDesc w = ds.d[m];
    int tot = w.K * w.N;
    if (i < tot) {
        int k = i / w.N, n = i - k * w.N;
        float v = w.src[i];
        unsigned short h = f2bf(v);
        w.dh[(size_t)n * w.K + k] = (short)h;
        w.dl[(size_t)n * w.K + k] = (short)f2bf(v - bf2f(h));
    }
}

__global__ void biascat_k(const float* __restrict__ bl, const float* __restrict__ br,
                          float* __restrict__ o) {
    int l = blockIdx.x, t = threadIdx.x;
    o[l * 256 + t] = (t < 128) ? bl[l * 128 + t] : br[l * 128 + (t - 128)];
}

// ---------------- LDS layout: [64][128] shorts, XOR-swizzled 16B chunks ----
template <int NTW>
__device__ inline void stage_mfma(
    const short* __restrict__ Wh, const short* __restrict__ Wl,
    int Kstride, int kb,
    const short (*Ash)[128], const short (*Asl)[128],
    int w, int llo, int lhi, f32x4 (&acc)[4][NTW])
{
#pragma unroll
    for (int ks = 0; ks < 4; ++ks) {
        bf16x8 wf_h[NTW], wf_l[NTW];
#pragma unroll
        for (int nt = 0; nt < NTW; ++nt) {
            int n = (w * NTW + nt) * 16 + llo;
            size_t off = (size_t)n * Kstride + kb + ks * 32 + lhi * 8;
            wf_h[nt] = *(const bf16x8*)(Wh + off);
            wf_l[nt] = *(const bf16x8*)(Wl + off);
        }
        bf16x8 ba_h[4], ba_l[4];
#pragma unroll
        for (int mt = 0; mt < 4; ++mt) {
            int m = mt * 16 + llo;
            int c = ((4 * ks + lhi) ^ llo) << 3;
            ba_h[mt] = *(const bf16x8*)&Ash[m][c];
            ba_l[mt] = *(const bf16x8*)&Asl[m][c];
        }
#pragma unroll
        for (int mt = 0; mt < 4; ++mt)
#pragma unroll
            for (int nt = 0; nt < NTW; ++nt) {
                acc[mt][nt] = __builtin_amdgcn_mfma_f32_16x16x32_bf16(
                    wf_h[nt], ba_h[mt], acc[mt][nt], 0, 0, 0);
                acc[mt][nt] = __builtin_amdgcn_mfma_f32_16x16x32_bf16(
                    wf_h[nt], ba_l[mt], acc[mt][nt], 0, 0, 0);
                acc[mt][nt] = __builtin_amdgcn_mfma_f32_16x16x32_bf16(
                    wf_l[nt], ba_h[mt], acc[mt][nt], 0, 0, 0);
            }
    }
}

// A plain bf16 (hi plane only): 2 MFMAs per product (a.wh + a.wl)
template <int NTW>
__device__ inline void stage_mfma_h(
    const short* __restrict__ Wh, const short* __restrict__ Wl,
    int Kstride, int kb,
    const short (*Ash)[128],
    int w, int llo, int lhi, f32x4 (&acc)[4][NTW])
{
#pragma unroll
    for (int ks = 0; ks < 4; ++ks) {
        bf16x8 wf_h[NTW], wf_l[NTW];
#pragma unroll
        for (int nt = 0; nt < NTW; ++nt) {
            int n = (w * NTW + nt) * 16 + llo;
            size_t off = (size_t)n * Kstride + kb + ks * 32 + lhi * 8;
            wf_h[nt] = *(const bf16x8*)(Wh + off);
            wf_l[nt] = *(const bf16x8*)(Wl + off);
        }
        bf16x8 ba[4];
#pragma unroll
        for (int mt = 0; mt < 4; ++mt) {
            int m = mt * 16 + llo;
            int c = ((4 * ks + lhi) ^ llo) << 3;
            ba[mt] = *(const bf16x8*)&Ash[m][c];
        }
#pragma unroll
        for (int mt = 0; mt < 4; ++mt)
#pragma unroll
            for (int nt = 0; nt < NTW; ++nt) {
                acc[mt][nt] = __builtin_amdgcn_mfma_f32_16x16x32_bf16(
                    wf_h[nt], ba[mt], acc[mt][nt], 0, 0, 0);
                acc[mt][nt] = __builtin_amdgcn_mfma_f32_16x16x32_bf16(
                    wf_l[nt], ba[mt], acc[mt][nt], 0, 0, 0);
            }
    }
}

// act = relu(acc + bias) -> split-bf16 back into LDS A planes (swizzled)
__device__ inline void act_to_lds(
    f32x4 (&acc)[4][2], const float* __restrict__ bias,
    short (*Ash)[128], short (*Asl)[128], int w, int llo, int lhi)
{
#pragma unroll
    for (int mt = 0; mt < 4; ++mt) {
        int r = mt * 16 + llo;
#pragma unroll
        for (int nt = 0; nt < 2; ++nt) {
            int c0 = (w * 2 + nt) * 16 + lhi * 4;
            int chunk = c0 >> 3;
            int off = ((chunk ^ llo) << 3) + (c0 & 7);
            short4 h4, l4;
            short* hp = (short*)&h4; short* lp = (short*)&l4;
#pragma unroll
            for (int u = 0; u < 4; ++u) {
                float z = acc[mt][nt][u] + bias[c0 + u];
                z = z > 0.f ? z : 0.f;
                unsigned short hb = f2bf(z);
                hp[u] = (short)hb;
                lp[u] = (short)f2bf(z - bf2f(hb));
            }
            *(short4*)&Ash[r][off] = h4;
            *(short4*)&Asl[r][off] = l4;
        }
    }
}

// act = relu(acc + bias) -> plain bf16 (hi only) into LDS
__device__ inline void act_to_lds_h(
    f32x4 (&acc)[4][2], const float* __restrict__ bias,
    short (*Ash)[128], int w, int llo, int lhi)
{
#pragma unroll
    for (int mt = 0; mt < 4; ++mt) {
        int r = mt * 16 + llo;
#pragma unroll
        for (int nt = 0; nt < 2; ++nt) {
            int c0 = (w * 2 + nt) * 16 + lhi * 4;
            int chunk = c0 >> 3;
            int off = ((chunk ^ llo) << 3) + (c0 & 7);
            short4 h4;
            short* hp = (short*)&h4;
#pragma unroll
            for (int u = 0; u < 4; ++u) {
                float z = acc[mt][nt][u] + bias[c0 + u];
                z = z > 0.f ? z : 0.f;
                hp[u] = (short)f2bf(z);
            }
            *(short4*)&Ash[r][off] = h4;
        }
    }
}

// per-thread register chunks for gather staging
struct AChunk { bf16x8 h[4], l[4]; };
struct AChunkH { bf16x8 h[4]; };

template <bool DUAL>
__device__ inline void gather_chunk(
    AChunk& c,
    const short* __restrict__ A0h, const short* __restrict__ A0l, int ld0, int K0,
    const short* __restrict__ A1h, const short* __restrict__ A1l, int ld1,
    const int* __restrict__ idx0, const int* __restrict__ idx1,
    int kb, int row0, int M, int t)
{
#pragma unroll
    for (int j = 0; j < 4; ++j) {
        int u = j * 256 + t;
        int lr = u >> 4, q = u & 15;
        int gr = row0 + lr; if (gr >= M) gr = M - 1;
        int kk = kb + q * 8;
        const short *bh, *bl; int ld, lk; const int* idx;
        if (!DUAL || kk < K0) { bh = A0h; bl = A0l; ld = ld0; lk = kk; idx = idx0; }
        else                  { bh = A1h; bl = A1l; ld = ld1; lk = kk - K0; idx = idx1; }
        int sr = idx ? idx[gr] : gr;
        size_t off = (size_t)sr * ld + lk;
        c.h[j] = *(const bf16x8*)(bh + off);
        c.l[j] = *(const bf16x8*)(bl + off);
    }
}

template <bool DUAL>
__device__ inline void gather_chunk_h(
    AChunkH& c,
    const short* __restrict__ A0, int ld0, int K0,
    const short* __restrict__ A1, int ld1,
    const int* __restrict__ idx0, const int* __restrict__ idx1,
    int kb, int row0, int M, int t)
{
#pragma unroll
    for (int j = 0; j < 4; ++j) {
        int u = j * 256 + t;
        int lr = u >> 4, q = u & 15;
        int gr = row0 + lr; if (gr >= M) gr = M - 1;
        int kk = kb + q * 8;
        const short* b; int ld, lk; const int* idx;
        if (!DUAL || kk < K0) { b = A0; ld = ld0; lk = kk; idx = idx0; }
        else                  { b = A1; ld = ld1; lk = kk - K0; idx = idx1; }
        int sr = idx ? idx[gr] : gr;
        c.h[j] = *(const bf16x8*)(b + (size_t)sr * ld + lk);
    }
}

__device__ inline void write_chunk(const AChunk& c,
                                   short (*Ash)[128], short (*Asl)[128], int t)
{
#pragma unroll
    for (int j = 0; j < 4; ++j) {
        int u = j * 256 + t;
        int lr = u >> 4, q = u & 15;
        int off = ((q ^ (lr & 15)) << 3);
        *(bf16x8*)&Ash[lr][off] = c.h[j];
        *(bf16x8*)&Asl[lr][off] = c.l[j];
    }
}

__device__ inline void write_chunk_h(const AChunkH& c, short (*Ash)[128], int t)
{
#pragma unroll
    for (int j = 0; j < 4; ++j) {
        int u = j * 256 + t;
        int lr = u >> 4, q = u & 15;
        int off = ((q ^ (lr & 15)) << 3);
        *(bf16x8*)&Ash[lr][off] = c.h[j];
    }
}

// ---------------- fused MLP chain (2 or 3 MFMA stages in one dispatch) -----
// h activations live interleaved: row stride 256 shorts, hi at +0, lo at +128.
// FINAL: 0 = write interleaved split rows (stride 256), 1 = FDOT sigmoid, 2 = fp32 NOUT.
// AHALF (edec): stage-1 A hi-plane-only, c0->As_h c1->As_l (1 barrier for both
// chunks); stage-2 activations plain bf16 (2-MFMA products). Sigmoid absorbs
// the bf16 rounding.
template <int K1, int NSTAGE, int NOUT, int FINAL, bool INS, bool AHALF>
__global__ __launch_bounds__(256, 2) void mlp_k(
    const void* __restrict__ A0h, const void* __restrict__ A0l, int ld0, int K0,
    const void* __restrict__ A1h, const void* __restrict__ A1l, int ld1,
    const int* __restrict__ idx0, const int* __restrict__ idx1,
    const short* __restrict__ W1h, const short* __restrict__ W1l, const float* __restrict__ b1,
    const short* __restrict__ W2h, const short* __restrict__ W2l, const float* __restrict__ b2,
    const short* __restrict__ W3h, const short* __restrict__ W3l, const float* __restrict__ b3,
    short* __restrict__ Ch, short* __restrict__ Cl, float* __restrict__ Cf,
    const float* __restrict__ Wd, const float* __restrict__ bd, float* __restrict__ outd,
    int M)
{
    __shared__ __align__(16) short As_h[64][128];
    __shared__ __align__(16) short As_l[64][128];
    __shared__ float redf[4][64];

    const int t = threadIdx.x;
    const int w = t >> 6, lane = t & 63;
    const int llo = lane & 15, lhi = lane >> 4;
    const int row0 = blockIdx.x * 64;

    // ---- stage 1 ----
    f32x4 acc1[4][2];
#pragma unroll
    for (int mt = 0; mt < 4; ++mt)
#pragma unroll
        for (int nt = 0; nt < 2; ++nt) { f32x4 z = {0,0,0,0}; acc1[mt][nt] = z; }

    if (AHALF) {
        // K1 == 256, hi-plane gathers; c0 -> As_h, c1 -> As_l, ONE barrier.
        AChunkH c0, c1;
        gather_chunk_h<true>(c0, (const short*)A0h, ld0, K0,
                             (const short*)A1h, ld1, idx0, idx1, 0, row0, M, t);
        gather_chunk_h<true>(c1, (const short*)A0h, ld0, K0,
                             (const short*)A1h, ld1, idx0, idx1, 128, row0, M, t);
        write_chunk_h(c0, As_h, t);
        write_chunk_h(c1, As_l, t);
        __syncthreads();
        stage_mfma_h<2>(W1h, W1l, K1, 0, As_h, w, llo, lhi, acc1);
        stage_mfma_h<2>(W1h, W1l, K1, 128, As_l, w, llo, lhi, acc1);
    } else if (INS) {
        AChunk c;
        gather_chunk<(K1 == 256)>(c, (const short*)A0h, (const short*)A0l, ld0, K0,
                                  (const short*)A1h, (const short*)A1l, ld1,
                                  idx0, idx1, 0, row0, M, t);
        write_chunk(c, As_h, As_l, t);
        __syncthreads();
        stage_mfma<2>(W1h, W1l, K1, 0, As_h, As_l, w, llo, lhi, acc1);
        if (K1 == 256) {
            __syncthreads();
            gather_chunk<true>(c, (const short*)A0h, (const short*)A0l, ld0, K0,
                               (const short*)A1h, (const short*)A1l, ld1,
                               idx0, idx1, 128, row0, M, t);
            write_chunk(c, As_h, As_l, t);
            __syncthreads();
            stage_mfma<2>(W1h, W1l, K1, 128, As_h, As_l, w, llo, lhi, acc1);
        }
    } else {
        // fp32 A (encoder layer 0): convert during staging, K1=128
#pragma unroll
        for (int j = 0; j < 8; ++j) {
            int u = j * 256 + t;
            int lr = u >> 5;
            int q  = u & 31;
            int gr = row0 + lr; if (gr >= M) gr = M - 1;
            int kk = q * 4;
            const float* src; int ld, lk; const int* idx;
            if (kk < K0) { src = (const float*)A0h; ld = ld0; lk = kk; idx = idx0; }
            else         { src = (const float*)A1h; ld = ld1; lk = kk - K0; idx = idx1; }
            int sr = idx ? idx[gr] : gr;
            float4 v = *(const float4*)(src + (size_t)sr * ld + lk);
            float xs[4] = {v.x, v.y, v.z, v.w};
            short4 h4, l4;
            short* hp = (short*)&h4; short* lp = (short*)&l4;
#pragma unroll
            for (int i = 0; i < 4; ++i) {
                unsigned short hb = f2bf(xs[i]);
                hp[i] = (short)hb;
                lp[i] = (short)f2bf(xs[i] - bf2f(hb));
            }
            int off = (((q >> 1) ^ (lr & 15)) << 3) + (q & 1) * 4;
            *(short4*)&As_h[lr][off] = h4;
            *(short4*)&As_l[lr][off] = l4;
        }
        __syncthreads();
        stage_mfma<2>(W1h, W1l, K1, 0, As_h, As_l, w, llo, lhi, acc1);
    }
    __syncthreads();                 // all stage-1 LDS reads done

    // ---- stage 2 ----
    f32x4 acc2[4][2];
#pragma unroll
    for (int mt = 0; mt < 4; ++mt)
#pragma unroll
        for (int nt = 0; nt < 2; ++nt) { f32x4 z = {0,0,0,0}; acc2[mt][nt] = z; }

    if (AHALF) {
        act_to_lds_h(acc1, b1, As_h, w, llo, lhi);
        __syncthreads();
        stage_mfma_h<2>(W2h, W2l, 128, 0, As_h, w, llo, lhi, acc2);
    } else {
        act_to_lds(acc1, b1, As_h, As_l, w, llo, lhi);
        __syncthreads();
        stage_mfma<2>(W2h, W2l, 128, 0, As_h, As_l, w, llo, lhi, acc2);
    }

    if (NSTAGE == 2) {
        // FDOT epilogue: out[r] = sigmoid(relu(acc2+b2) . Wd + bd)
        const float bdd = bd[0];
        float pd[4] = {0.f, 0.f, 0.f, 0.f};
#pragma unroll
        for (int mt = 0; mt < 4; ++mt)
#pragma unroll
            for (int nt = 0; nt < 2; ++nt) {
                int c0 = (w * 2 + nt) * 16 + lhi * 4;
#pragma unroll
                for (int u = 0; u < 4; ++u) {
                    float z = acc2[mt][nt][u] + b2[c0 + u];
                    z = z > 0.f ? z : 0.f;
                    pd[mt] = fmaf(z, Wd[c0 + u], pd[mt]);
                }
            }
#pragma unroll
        for (int mt = 0; mt < 4; ++mt) {
            pd[mt] += __shfl_xor(pd[mt], 16, 64);
            pd[mt] += __shfl_xor(pd[mt], 32, 64);
        }
        if (lhi == 0) {
#pragma unroll
            for (int mt = 0; mt < 4; ++mt) redf[w][mt * 16 + llo] = pd[mt];
        }
        __syncthreads();
        if (w == 0 && lhi == 0) {
#pragma unroll
            for (int mt = 0; mt < 4; ++mt) {
                int r = row0 + mt * 16 + llo;
                if (r < M) {
                    float d = redf[0][mt * 16 + llo] + redf[1][mt * 16 + llo]
                            + redf[2][mt * 16 + llo] + redf[3][mt * 16 + llo] + bdd;
                    outd[r] = 1.f / (1.f + __expf(-d));
                }
            }
        }
    } else {
        __syncthreads();
        act_to_lds(acc2, b2, As_h, As_l, w, llo, lhi);
        __syncthreads();
        // ---- stage 3 ----
        constexpr int NTWF = NOUT / 64;
        f32x4 acc3[4][NTWF];
#pragma unroll
        for (int mt = 0; mt < 4; ++mt)
#pragma unroll
            for (int nt = 0; nt < NTWF; ++nt) { f32x4 z = {0,0,0,0}; acc3[mt][nt] = z; }
        stage_mfma<NTWF>(W3h, W3l, 128, 0, As_h, As_l, w, llo, lhi, acc3);
#pragma unroll
        for (int mt = 0; mt < 4; ++mt) {
            int r = row0 + mt * 16 + llo;
            if (r < M) {
#pragma unroll
                for (int nt = 0; nt < NTWF; ++nt) {
                    int c0 = (w * NTWF + nt) * 16 + lhi * 4;
                    float v[4];
#pragma unroll
                    for (int u = 0; u < 4; ++u) v[u] = acc3[mt][nt][u] + b3[c0 + u];
                    if (FINAL == 0) {
                        short4 h4, l4;
                        short* hp = (short*)&h4; short* lp = (short*)&l4;
#pragma unroll
                        for (int u = 0; u < 4; ++u) {
                            unsigned short hb = f2bf(v[u]);
                            hp[u] = (short)hb;
                            lp[u] = (short)f2bf(v[u] - bf2f(hb));
                        }
                        *(short4*)(Ch + (size_t)r * 256 + c0) = h4;   // interleaved rows
                        *(short4*)(Cl + (size_t)r * 256 + c0) = l4;   // Cl = Ch + 128
                    } else {
                        float4 o = {v[0], v[1], v[2], v[3]};
                        *(float4*)(Cf + (size_t)r * NOUT + c0) = o;
                    }
                }
            }
        }
    }
}

// ---------------- N=256 GEMM for fused xl||xr -> bf16 rows [NN][256] -------
__global__ __launch_bounds__(256, 2) void gemmlr_k(
    const short* __restrict__ h,     // interleaved split rows, stride 256
    const short* __restrict__ Wh, const short* __restrict__ Wl,
    const float* __restrict__ bias, short* __restrict__ C, int M)
{
    __shared__ __align__(16) short As_h[64][128];
    __shared__ __align__(16) short As_l[64][128];
    const int t = threadIdx.x;
    const int w = t >> 6, lane = t & 63;
    const int llo = lane & 15, lhi = lane >> 4;
    const int row0 = blockIdx.x * 64;

    f32x4 acc[4][4];
#pragma unroll
    for (int mt = 0; mt < 4; ++mt)
#pragma unroll
        for (int nt = 0; nt < 4; ++nt) { f32x4 z = {0,0,0,0}; acc[mt][nt] = z; }

#pragma unroll
    for (int j = 0; j < 4; ++j) {
        int u = j * 256 + t;
        int lr = u >> 4;
        int q  = u & 15;
        int gr = row0 + lr; if (gr >= M) gr = M - 1;
        size_t off = (size_t)gr * 256 + q * 8;
        int loff = ((q ^ (lr & 15)) << 3);
        *(bf16x8*)&As_h[lr][loff] = *(const bf16x8*)(h + off);
        *(bf16x8*)&As_l[lr][loff] = *(const bf16x8*)(h + off + 128);
    }
    __syncthreads();
    stage_mfma<4>(Wh, Wl, 128, 0, As_h, As_l, w, llo, lhi, acc);

#pragma unroll
    for (int mt = 0; mt < 4; ++mt) {
        int r = row0 + mt * 16 + llo;
        if (r < M) {
#pragma unroll
            for (int nt = 0; nt < 4; ++nt) {
                int c0 = (w * 4 + nt) * 16 + lhi * 4;
                short4 o;
                short* op = (short*)&o;
#pragma unroll
                for (int u = 0; u < 4; ++u)
                    op[u] = (short)f2bf(acc[mt][nt][u] + bias[c0 + u]);
                *(short4*)(C + (size_t)r * 256 + c0) = o;
            }
        }
    }
}

// ---------------- GATv2: half-wave per edge, bf16 rows, DPP logit reduce ---
#define GPH 4
#define NEGI -1e30f
#define DPPADD(v, ctrl) \
    v += __int_as_float(__builtin_amdgcn_update_dpp(0, __float_as_int(v), ctrl, 0xf, 0xf, true))

__device__ inline float red32_bcast(float v) {
    DPPADD(v, 0x111);   // row_shr:1
    DPPADD(v, 0x112);   // row_shr:2
    DPPADD(v, 0x114);   // row_shr:4
    DPPADD(v, 0x118);   // row_shr:8
    DPPADD(v, 0x142);   // row_bcast15 -> lane31 holds 32-sum
    return __int_as_float(__builtin_amdgcn_ds_swizzle(__float_as_int(v), 0x03E0));
}

__global__ __launch_bounds__(256) void gat2_k(
    const short* __restrict__ xlr,   // bf16 rows [NN][256]: xl | xr
    const float* __restrict__ att,
    const int* __restrict__ offs, const int* __restrict__ csrs,
    const float* __restrict__ bias,
    short* __restrict__ hout)        // interleaved split rows, stride 256
{
    const int wid = (blockIdx.x * 256 + threadIdx.x) >> 6;
    const int lane = threadIdx.x & 63;
    const int h = lane >> 5, sub = lane & 31;
    if (wid >= NN) return;
    const int n = wid;
    const int beg = offs[n];
    const int total = (offs[n + 1] - beg) + 1;

    const float4 attv = *(const float4*)(att + sub * 4);
    const float4 xrv  = ld_bf4(xlr + (size_t)n * 256 + 128 + sub * 4);

    float m = NEGI, s = 0.f;
    float4 acc = {0.f, 0.f, 0.f, 0.f};

    int cs[GPH];
#pragma unroll
    for (int p = 0; p < GPH; ++p) {
        int slot = p * 2 + h;
        cs[p] = (slot < total) ? ((slot == 0) ? n : csrs[beg + slot - 1]) : n;
    }

    for (int base = 0; base < total; base += 2 * GPH) {
        float4 r[GPH];
#pragma unroll
        for (int p = 0; p < GPH; ++p)
            r[p] = ld_bf4(xlr + (size_t)cs[p] * 256 + sub * 4);
        int ns[GPH];
#pragma unroll
        for (int p = 0; p < GPH; ++p) {
            int nslot = base + 2 * GPH + p * 2 + h;
            ns[p] = (nslot < total) ? csrs[beg + nslot - 1] : n;
        }
        float e[GPH];
#pragma unroll
        for (int p = 0; p < GPH; ++p) {
            float v = 0.f;
#pragma unroll
            for (int j = 0; j < 4; ++j) {
                float mj = ((const float*)&r[p])[j] + ((const float*)&xrv)[j];
                mj = mj > 0.f ? mj : 0.2f * mj;
                v = fmaf(mj, ((const float*)&attv)[j], v);
            }
            v = red32_bcast(v);
            e[p] = (base + p * 2 + h < total) ? v : NEGI;
        }
        float tm = fmaxf(fmaxf(e[0], e[1]), fmaxf(e[2], e[3]));
        float mnew = fmaxf(m, tm);
        float sc = __expf(m - mnew);
        s *= sc; acc.x *= sc; acc.y *= sc; acc.z *= sc; acc.w *= sc;
#pragma unroll
        for (int p = 0; p < GPH; ++p) {
            float wj = __expf(e[p] - mnew);
            s += wj;
            acc.x = fmaf(wj, r[p].x, acc.x);
            acc.y = fmaf(wj, r[p].y, acc.y);
            acc.z = fmaf(wj, r[p].z, acc.z);
            acc.w = fmaf(wj, r[p].w, acc.w);
        }
        m = mnew;
#pragma unroll
        for (int p = 0; p < GPH; ++p) cs[p] = ns[p];
    }
    // merge halves
    float om = __shfl_xor(m, 32, 64);
    float os = __shfl_xor(s, 32, 64);
    float4 oacc;
    oacc.x = __shfl_xor(acc.x, 32, 64);
    oacc.y = __shfl_xor(acc.y, 32, 64);
    oacc.z = __shfl_xor(acc.z, 32, 64);
    oacc.w = __shfl_xor(acc.w, 32, 64);
    float M = fmaxf(m, om);
    float a = __expf(m - M), b = __expf(om - M);
    float st = s * a + os * b;
    float inv = 1.f / st;
    if (h == 0) {
        float ov[4];
        ov[0] = (acc.x * a + oacc.x * b) * inv + bias[sub * 4 + 0];
        ov[1] = (acc.y * a + oacc.y * b) * inv + bias[sub * 4 + 1];
        ov[2] = (acc.z * a + oacc.z * b) * inv + bias[sub * 4 + 2];
        ov[3] = (acc.w * a + oacc.w * b) * inv + bias[sub * 4 + 3];
        short4 h4, l4;
        short* hp = (short*)&h4; short* lp = (short*)&l4;
#pragma unroll
        for (int u = 0; u < 4; ++u) {
            unsigned short hb = f2bf(ov[u]);
            hp[u] = (short)hb;
            lp[u] = (short)f2bf(ov[u] - bf2f(hb));
        }
        *(short4*)(hout + (size_t)n * 256 + sub * 4) = h4;
        *(short4*)(hout + (size_t)n * 256 + 128 + sub * 4) = l4;
    }
}

extern "C" void kernel_launch(void* const* d_in, const int* in_sizes, int n_in,
                              void* d_out, int out_size, void* d_ws, size_t ws_size,
                              hipStream_t stream)
{
    const float* x    = (const float*)d_in[0];
    const float* emb  = (const float*)d_in[1];
    const int*   ei   = (const int*)d_in[2];
    const int*   bidx = (const int*)d_in[3];
    const int*   eim  = (const int*)d_in[4];
    const float* encW = (const float*)d_in[5];
    const float* encB = (const float*)d_in[6];
    const float* gWl  = (const float*)d_in[7];
    const float* gbl  = (const float*)d_in[8];
    const float* gWr  = (const float*)d_in[9];
    const float* gbr  = (const float*)d_in[10];
    const float* gatt = (const float*)d_in[11];
    const float* gb   = (const float*)d_in[12];
    const float* eW0  = (const float*)d_in[13];
    const float* eb0  = (const float*)d_in[14];
    const float* eW1  = (const float*)d_in[15];
    const float* eb1  = (const float*)d_in[16];
    const float* eW2  = (const float*)d_in[17];
    const float* eb2  = (const float*)d_in[18];
    const float* nW0  = (const float*)d_in[19];
    const float* nb0  = (const float*)d_in[20];
    const float* nW1  = (const float*)d_in[21];
    const float* nb1  = (const float*)d_in[22];
    const float* nW2  = (const float*)d_in[23];
    const float* nb2  = (const float*)d_in[24];
    float* out = (float*)d_out;

    char* wptr = (char*)d_ws;
    auto alloc = [&](size_t bytes) {
        char* p = wptr;
        wptr += (bytes + 255) & ~(size_t)255;
        return p;
    };
    short* h    = (short*)alloc((size_t)NN * 256 * 2);   // interleaved hi|lo rows
    short* xlrb = (short*)alloc((size_t)NN * 256 * 2);   // bf16 xl|xr rows
    int* counts = (int*)alloc((size_t)NN * 4);
    int* offs   = (int*)alloc((size_t)(NN + 1) * 4);
    int* csrs   = (int*)alloc((size_t)NE * 4);
    int* bsum   = (int*)alloc(256 * 4);
    int* bscan  = (int*)alloc(256 * 4);
    auto wplane = [&](int elems, short*& ph, short*& pl) {
        ph = (short*)alloc((size_t)elems * 2);
        pl = (short*)alloc((size_t)elems * 2);
    };
    short *encWt_h[3], *encWt_l[3];
    for (int i = 0; i < 3; ++i) wplane(HID * HID, encWt_h[i], encWt_l[i]);
    short *glrt_h[3], *glrt_l[3];
    for (int i = 0; i < 3; ++i) wplane(256 * HID, glrt_h[i], glrt_l[i]);
    short *eW0t_h, *eW0t_l, *eW1t_h, *eW1t_l;
    wplane(2 * HID * HID, eW0t_h, eW0t_l);
    wplane(HID * HID, eW1t_h, eW1t_l);
    short *nW0t_h, *nW0t_l, *nW1t_h, *nW1t_l, *nW2t_h, *nW2t_l;
    wplane(HID * HID, nW0t_h, nW0t_l);
    wplane(HID * HID, nW1t_h, nW1t_l);
    wplane(HID * 64, nW2t_h, nW2t_l);
    float* gblr = (float*)alloc(3 * 256 * 4);

    // ---- W pre-conversion ----
    WDescs ds;
    int di = 0;
    for (int i = 0; i < 3; ++i)
        ds.d[di++] = {encW + (size_t)i * HID * HID, encWt_h[i], encWt_l[i], HID, HID};
    for (int i = 0; i < 3; ++i) {
        ds.d[di++] = {gWl + (size_t)i * HID * HID, glrt_h[i], glrt_l[i], HID, HID};
        ds.d[di++] = {gWr + (size_t)i * HID * HID, glrt_h[i] + HID * HID,
                      glrt_l[i] + HID * HID, HID, HID};
    }
    ds.d[di++] = {eW0, eW0t_h, eW0t_l, 2 * HID, HID};
    ds.d[di++] = {eW1, eW1t_h, eW1t_l, HID, HID};
    ds.d[di++] = {nW0, nW0t_h, nW0t_l, HID, HID};
    ds.d[di++] = {nW1, nW1t_h, nW1t_l, HID, HID};
    ds.d[di++] = {nW2, nW2t_h, nW2t_l, HID, 64};
    wconv_k<<<14 * 128, 256, 0, stream>>>(ds);
    biascat_k<<<3, 256, 0, stream>>>(gbl, gbr, gblr);

    // ---- CSR build ----
    zero_k<<<(NN + 255) / 256, 256, 0, stream>>>(counts, NN);
    count_k<<<(NE + 255) / 256, 256, 0, stream>>>(ei, counts);
    scan1_k<<<NB_SCAN, 256, 0, stream>>>(counts, offs, bsum);
    scan2_k<<<1, 256, 0, stream>>>(bsum, bscan, offs);
    scan3_k<<<NB_SCAN, 256, 0, stream>>>(offs, bscan);
    scatter_k<<<(NE + 255) / 256, 256, 0, stream>>>(ei, offs, counts, csrs);

    const int gN = (NN + 63) / 64;
    // ---- encoder MLP: one fused dispatch (3 stages) -> interleaved h ----
    mlp_k<128, 3, 128, 0, false, false><<<gN, 256, 0, stream>>>(
        x, nullptr, 64, 64, emb, nullptr, 64, nullptr, nullptr,
        encWt_h[0], encWt_l[0], encB,
        encWt_h[1], encWt_l[1], encB + 128,
        encWt_h[2], encWt_l[2], encB + 256,
        h, h + 128, nullptr, nullptr, nullptr, nullptr, NN);

    // ---- 3 GATv2 layers ----
    const int gGAT = (NN * 64 + 255) / 256;
    for (int l = 0; l < 3; ++l) {
        gemmlr_k<<<gN, 256, 0, stream>>>(h, glrt_h[l], glrt_l[l],
                                         gblr + (size_t)l * 256, xlrb, NN);
        gat2_k<<<gGAT, 256, 0, stream>>>(xlrb, gatt + (size_t)l * HID,
                                         offs, csrs, gb + (size_t)l * HID, h);
    }

    // ---- edge decoder: single fused dispatch, hi-plane gathers ----
    mlp_k<256, 2, 128, 1, true, true><<<(NIMAG + 63) / 64, 256, 0, stream>>>(
        h, nullptr, 256, 128, h, nullptr, 256, eim, eim + NIMAG,
        eW0t_h, eW0t_l, eb0,
        eW1t_h, eW1t_l, eb1,
        nullptr, nullptr, nullptr,
        nullptr, nullptr, nullptr,
        eW2, eb2, out + (size_t)NBLOCK * 64, NIMAG);

    // ---- node decoder: one fused dispatch (3 stages) ----
    mlp_k<128, 3, 64, 2, true, false><<<(NBLOCK + 63) / 64, 256, 0, stream>>>(
        h, h + 128, 256, 128, nullptr, nullptr, 0, bidx, nullptr,
        nW0t_h, nW0t_l, nb0,
        nW1t_h, nW1t_l, nb1,
        nW2t_h, nW2t_l, nb2,
        nullptr, nullptr, out, nullptr, nullptr, nullptr, NBLOCK);
}